// Round 5
// baseline (299.306 us; speedup 1.0000x reference)
//
#include <hip/hip_runtime.h>
#include <math.h>

#define BATCH 8192
#define FEAT  256
#define NCLS  1000

#define NGEMM  256                  // 16x16 grid of 64x64 inter tiles
#define REPL   4                    // replica blocks per class (tail killer)
#define NBLK   (NGEMM + REPL*NCLS)  // 4256
#define ROWCAP 24                   // rows staged in LDS per class
#define MEMCAP 96                   // hard cap on class size (P(n>40) ~ 1e-15)

// ws (u32): [0]=intra max bits (memset 0), [1]=done counter (memset 0),
//           [2]=inter min bits (memset 0xFF -> uint max)

// LDS union:
//   GEMM : As[32][68] (8704) | Bs[32][68] (8704) | cmagS[64] (256)  = 17664 B
//   intra: rowS[24][256] (24576) | mem[96] (384) | magS[96] (384)   = 25344 B
__global__ __launch_bounds__(256) void k_main(const float* __restrict__ x,
                                              const int* __restrict__ labels,
                                              const float* __restrict__ centers,
                                              unsigned int* __restrict__ scal,
                                              float* __restrict__ out) {
    __shared__ __align__(16) char raw[25408];
    __shared__ int cnt;
    int t = threadIdx.x;
    int lane = t & 63, w = t >> 6;

    if (blockIdx.x < NGEMM) {
        // ---------------- inter: 64x64 f32 tile, 4x4 register blocking ----
        float (*As)[68] = reinterpret_cast<float(*)[68]>(raw);
        float (*Bs)[68] = reinterpret_cast<float(*)[68]>(raw + 8704);
        float* cmagS    = reinterpret_cast<float*>(raw + 17408);
        int bi = blockIdx.x >> 4, bj = blockIdx.x & 15;
        int i0 = bi * 64, j0 = bj * 64;

        // inline cmag for this tile's j-rows (bit-exact rownorm tree)
        for (int q = w; q < 64; q += 4) {
            int gj = j0 + q;
            float s = 0.0f;
            if (gj < NCLS) {
                float4 v = reinterpret_cast<const float4*>(centers + (size_t)gj * FEAT)[lane];
                s = v.x * v.x + v.y * v.y + v.z * v.z + v.w * v.w;
                #pragma unroll
                for (int o = 32; o > 0; o >>= 1) s += __shfl_xor(s, o);
            }
            if (lane == 0) cmagS[q] = 2.0f * s;
        }
        // (k-loop barriers below order cmagS writes before the epilogue reads)

        int tx = t & 15, ty = t >> 4;
        float acc[4][4] = {{0.f}};
        for (int kk = 0; kk < FEAT; kk += 32) {
            #pragma unroll
            for (int e = t; e < 512; e += 256) {
                int row = e >> 3, q = e & 7;
                int col = kk + q * 4;
                int gi = i0 + row, gj = j0 + row;
                float4 av = (gi < NCLS)
                    ? *reinterpret_cast<const float4*>(centers + (size_t)gi * FEAT + col)
                    : make_float4(0.f, 0.f, 0.f, 0.f);
                float4 bv = (gj < NCLS)
                    ? *reinterpret_cast<const float4*>(centers + (size_t)gj * FEAT + col)
                    : make_float4(0.f, 0.f, 0.f, 0.f);
                As[q * 4 + 0][row] = av.x; As[q * 4 + 1][row] = av.y;
                As[q * 4 + 2][row] = av.z; As[q * 4 + 3][row] = av.w;
                Bs[q * 4 + 0][row] = bv.x; Bs[q * 4 + 1][row] = bv.y;
                Bs[q * 4 + 2][row] = bv.z; Bs[q * 4 + 3][row] = bv.w;
            }
            __syncthreads();
            #pragma unroll
            for (int k = 0; k < 32; ++k) {   // sequential k: same rounding as before
                float4 a4 = *reinterpret_cast<float4*>(&As[k][ty * 4]);
                float4 b4 = *reinterpret_cast<float4*>(&Bs[k][tx * 4]);
                acc[0][0] += a4.x * b4.x; acc[0][1] += a4.x * b4.y;
                acc[0][2] += a4.x * b4.z; acc[0][3] += a4.x * b4.w;
                acc[1][0] += a4.y * b4.x; acc[1][1] += a4.y * b4.y;
                acc[1][2] += a4.y * b4.z; acc[1][3] += a4.y * b4.w;
                acc[2][0] += a4.z * b4.x; acc[2][1] += a4.z * b4.y;
                acc[2][2] += a4.z * b4.z; acc[2][3] += a4.z * b4.w;
                acc[3][0] += a4.w * b4.x; acc[3][1] += a4.w * b4.y;
                acc[3][2] += a4.w * b4.z; acc[3][3] += a4.w * b4.w;
            }
            __syncthreads();
        }
        float lmin = 1e30f;
        #pragma unroll
        for (int jj = 0; jj < 4; ++jj) {
            int j = j0 + tx * 4 + jj;
            if (j < NCLS) {
                float cm = cmagS[tx * 4 + jj];
                #pragma unroll
                for (int ii = 0; ii < 4; ++ii) {
                    int i = i0 + ty * 4 + ii;
                    if (i < NCLS) {
                        float v = cm - 2.0f * acc[ii][jj];
                        v = fminf(fmaxf(v, 1e-12f), 1e12f);
                        lmin = fminf(lmin, v);
                    }
                }
            }
        }
        #pragma unroll
        for (int o = 32; o > 0; o >>= 1) lmin = fminf(lmin, __shfl_xor(lmin, o));
        if ((t & 63) == 0) atomicMin(scal + 2, __float_as_uint(lmin));
    } else {
        // ---------------- intra: class-owned replica blocks ----------------
        int bid = blockIdx.x - NGEMM;
        int c   = bid >> 2;            // class id 0..999
        int r   = bid & 3;             // replica 0..3
        float (*rowS)[256] = reinterpret_cast<float(*)[256]>(raw);
        int*   mem  = reinterpret_cast<int*>(raw + 24576);
        float* magS = reinterpret_cast<float*>(raw + 24960);

        if (t == 0) cnt = 0;
        __syncthreads();
        // find members: coalesced int4 scan of labels (L2-resident, 32KB)
        const int4* gl4 = reinterpret_cast<const int4*>(labels);
        #pragma unroll
        for (int k = 0; k < 8; ++k) {
            int4 lv = gl4[t + (k << 8)];
            int base = (t + (k << 8)) << 2;
            if (lv.x == c) { int p = atomicAdd(&cnt, 1); if (p < MEMCAP) mem[p] = base;     }
            if (lv.y == c) { int p = atomicAdd(&cnt, 1); if (p < MEMCAP) mem[p] = base + 1; }
            if (lv.z == c) { int p = atomicAdd(&cnt, 1); if (p < MEMCAP) mem[p] = base + 2; }
            if (lv.w == c) { int p = atomicAdd(&cnt, 1); if (p < MEMCAP) mem[p] = base + 3; }
        }
        __syncthreads();
        int n = cnt < MEMCAP ? cnt : MEMCAP;
        if (n >= 2) {
            const float4* x4 = reinterpret_cast<const float4*>(x);
            // stage rows + tree mags (bit-exact shuffle tree, as before)
            for (int m = w; m < n; m += 4) {
                int row = mem[m];
                float4 v = x4[(size_t)row * 64 + lane];
                if (m < ROWCAP)
                    *reinterpret_cast<float4*>(&rowS[m][lane << 2]) = v;
                float s = v.x * v.x + v.y * v.y + v.z * v.z + v.w * v.w;
                #pragma unroll
                for (int o = 32; o > 0; o >>= 1) s += __shfl_xor(s, o);
                if (lane == 0) magS[m] = s;
            }
            __syncthreads();
            int npairs = n * (n - 1) / 2;
            float vmax = 0.0f;
            for (int p = r * 4 + w; p < npairs; p += 16) {   // residue-unique pairs
                int a = 0, rem = p;                           // unrank (a-major)
                while (rem >= n - 1 - a) { rem -= n - 1 - a; ++a; }
                int b = a + 1 + rem;
                float4 va = (a < ROWCAP)
                    ? *reinterpret_cast<float4*>(&rowS[a][lane << 2])
                    : x4[(size_t)mem[a] * 64 + lane];
                float4 vb = (b < ROWCAP)
                    ? *reinterpret_cast<float4*>(&rowS[b][lane << 2])
                    : x4[(size_t)mem[b] * 64 + lane];
                float s = va.x * vb.x + va.y * vb.y + va.z * vb.z + va.w * vb.w;
                #pragma unroll
                for (int o = 32; o > 0; o >>= 1) s += __shfl_xor(s, o);
                float d2 = magS[a] + magS[b] - 2.0f * s;     // add commutes: bit-same
                float d  = sqrtf(fmaxf(d2, 0.0f));
                d = fminf(fmaxf(d, 1e-12f), 1e12f);
                vmax = fmaxf(vmax, d);
            }
            if (lane == 0 && vmax > 0.0f)
                atomicMax(scal + 0, __float_as_uint(vmax));
        }
    }

    // ---------------- last-done block combines the scalars ----------------
    __syncthreads();
    if (threadIdx.x == 0) {
        __threadfence();
        unsigned int done = atomicAdd(scal + 1, 1u);
        if (done == NBLK - 1) {
            float M = fmaxf(__uint_as_float(atomicOr(scal + 0, 0u)), 1e-12f); // diag floor
            float rr = 1.0f / M;
            float li2 = 2.0f / (rr + rr);                 // harmonic mean of [M,M] * 2
            float m = fminf(__uint_as_float(atomicOr(scal + 2, 0u)), 1e12f);
            float linter = fminf(fmaxf(5.0f - m, 0.0f), 1e6f);
            out[0] = li2 + linter;                        // ALPHA = BETA = 1
        }
    }
}

extern "C" void kernel_launch(void* const* d_in, const int* in_sizes, int n_in,
                              void* d_out, int out_size, void* d_ws, size_t ws_size,
                              hipStream_t stream) {
    const float* x       = (const float*)d_in[0];
    const int*   labels  = (const int*)d_in[1];
    const float* centers = (const float*)d_in[2];
    unsigned int* scal   = (unsigned int*)d_ws;
    float*        out    = (float*)d_out;

    // [0]=intra max (0), [1]=done counter (0), [2]=inter min (0xFFFFFFFF)
    hipMemsetAsync(scal, 0x00, 8, stream);
    hipMemsetAsync((char*)d_ws + 8, 0xFF, 4, stream);

    k_main<<<NBLK, 256, 0, stream>>>(x, labels, centers, scal, out);
}

// Round 6
// 95.532 us; speedup vs baseline: 3.1330x; 3.1330x over previous
//
#include <hip/hip_runtime.h>
#include <math.h>

#define BATCH 8192
#define FEAT  256
#define NCLS  1000

#define NGEMM  256                  // 16x16 grid of 64x64 inter tiles
#define REPL   4                    // replica blocks per class (tail killer)
#define NBLK   (NGEMM + REPL*NCLS)  // 4256
#define ROWCAP 16                   // rows staged in LDS per class
#define MEMCAP 96                   // hard cap on class size (P(n>40) ~ 1e-15)
#define NSLOT  64                   // reduction slots, one 64B line each

// ws layout (u32 indices): umax slots  [slot*16]        for slot in [0,64)
//                          uminC slots [1024 + slot*16] (complemented min)
// Single hipMemsetAsync(0) covers both: umax empty=0 (< any positive float bits),
// uminC empty=0 (< any complemented positive float bits). Min over positive f32
// == ~(max over ~bits) exactly (unsigned order reversal).

// LDS union:
//   GEMM : As[32][68] (8704) | Bs[32][68] (8704) | cmagS[64] (256) = 17664 B
//   intra: rowS[16][256] (16384) | mem[96] (384) | magS[96] (384)  = 17152 B
__global__ __launch_bounds__(256) void k_main(const float* __restrict__ x,
                                              const int* __restrict__ labels,
                                              const float* __restrict__ centers,
                                              unsigned int* __restrict__ ws,
                                              float* __restrict__ out) {
    __shared__ __align__(16) char raw[17664];
    __shared__ float wred[4];
    __shared__ int cnt;
    int t = threadIdx.x;
    int lane = t & 63, w = t >> 6;

    if (blockIdx.x < NGEMM) {
        // ---------------- inter: 64x64 f32 tile, 4x4 register blocking ----
        float (*As)[68] = reinterpret_cast<float(*)[68]>(raw);
        float (*Bs)[68] = reinterpret_cast<float(*)[68]>(raw + 8704);
        float* cmagS    = reinterpret_cast<float*>(raw + 17408);
        int bi = blockIdx.x >> 4, bj = blockIdx.x & 15;
        int i0 = bi * 64, j0 = bj * 64;

        // inline cmag for this tile's j-rows (bit-exact rownorm tree)
        for (int q = w; q < 64; q += 4) {
            int gj = j0 + q;
            float s = 0.0f;
            if (gj < NCLS) {
                float4 v = reinterpret_cast<const float4*>(centers + (size_t)gj * FEAT)[lane];
                s = v.x * v.x + v.y * v.y + v.z * v.z + v.w * v.w;
                #pragma unroll
                for (int o = 32; o > 0; o >>= 1) s += __shfl_xor(s, o);
            }
            if (lane == 0) cmagS[q] = 2.0f * s;
        }
        // (k-loop barriers below order cmagS writes before the epilogue reads)

        int tx = t & 15, ty = t >> 4;
        float acc[4][4] = {{0.f}};
        for (int kk = 0; kk < FEAT; kk += 32) {
            #pragma unroll
            for (int e = t; e < 512; e += 256) {
                int row = e >> 3, q = e & 7;
                int col = kk + q * 4;
                int gi = i0 + row, gj = j0 + row;
                float4 av = (gi < NCLS)
                    ? *reinterpret_cast<const float4*>(centers + (size_t)gi * FEAT + col)
                    : make_float4(0.f, 0.f, 0.f, 0.f);
                float4 bv = (gj < NCLS)
                    ? *reinterpret_cast<const float4*>(centers + (size_t)gj * FEAT + col)
                    : make_float4(0.f, 0.f, 0.f, 0.f);
                As[q * 4 + 0][row] = av.x; As[q * 4 + 1][row] = av.y;
                As[q * 4 + 2][row] = av.z; As[q * 4 + 3][row] = av.w;
                Bs[q * 4 + 0][row] = bv.x; Bs[q * 4 + 1][row] = bv.y;
                Bs[q * 4 + 2][row] = bv.z; Bs[q * 4 + 3][row] = bv.w;
            }
            __syncthreads();
            #pragma unroll
            for (int k = 0; k < 32; ++k) {   // sequential k: same rounding as before
                float4 a4 = *reinterpret_cast<float4*>(&As[k][ty * 4]);
                float4 b4 = *reinterpret_cast<float4*>(&Bs[k][tx * 4]);
                acc[0][0] += a4.x * b4.x; acc[0][1] += a4.x * b4.y;
                acc[0][2] += a4.x * b4.z; acc[0][3] += a4.x * b4.w;
                acc[1][0] += a4.y * b4.x; acc[1][1] += a4.y * b4.y;
                acc[1][2] += a4.y * b4.z; acc[1][3] += a4.y * b4.w;
                acc[2][0] += a4.z * b4.x; acc[2][1] += a4.z * b4.y;
                acc[2][2] += a4.z * b4.z; acc[2][3] += a4.z * b4.w;
                acc[3][0] += a4.w * b4.x; acc[3][1] += a4.w * b4.y;
                acc[3][2] += a4.w * b4.z; acc[3][3] += a4.w * b4.w;
            }
            __syncthreads();
        }
        float lmin = 1e30f;
        #pragma unroll
        for (int jj = 0; jj < 4; ++jj) {
            int j = j0 + tx * 4 + jj;
            if (j < NCLS) {
                float cm = cmagS[tx * 4 + jj];
                #pragma unroll
                for (int ii = 0; ii < 4; ++ii) {
                    int i = i0 + ty * 4 + ii;
                    if (i < NCLS) {
                        float v = cm - 2.0f * acc[ii][jj];
                        v = fminf(fmaxf(v, 1e-12f), 1e12f);
                        lmin = fminf(lmin, v);
                    }
                }
            }
        }
        #pragma unroll
        for (int o = 32; o > 0; o >>= 1) lmin = fminf(lmin, __shfl_xor(lmin, o));
        if (lane == 0) wred[w] = lmin;
        __syncthreads();
        if (t == 0) {
            float m = fminf(fminf(wred[0], wred[1]), fminf(wred[2], wred[3]));
            unsigned int bits = ~__float_as_uint(m);      // complement: min -> max
            volatile unsigned int* p = ws + 1024 + (blockIdx.x & (NSLOT - 1)) * 16;
            if (bits > *p) atomicMax((unsigned int*)p, bits);
        }
    } else {
        // ---------------- intra: class-owned replica blocks ----------------
        int bid = blockIdx.x - NGEMM;
        int c   = bid >> 2;            // class id 0..999
        int r   = bid & 3;             // replica 0..3
        float (*rowS)[256] = reinterpret_cast<float(*)[256]>(raw);
        int*   mem  = reinterpret_cast<int*>(raw + 16384);
        float* magS = reinterpret_cast<float*>(raw + 16768);

        if (t == 0) cnt = 0;
        __syncthreads();
        // find members: coalesced int4 scan of labels (L2-resident, 32KB)
        const int4* gl4 = reinterpret_cast<const int4*>(labels);
        #pragma unroll
        for (int k = 0; k < 8; ++k) {
            int4 lv = gl4[t + (k << 8)];
            int base = (t + (k << 8)) << 2;
            if (lv.x == c) { int p = atomicAdd(&cnt, 1); if (p < MEMCAP) mem[p] = base;     }
            if (lv.y == c) { int p = atomicAdd(&cnt, 1); if (p < MEMCAP) mem[p] = base + 1; }
            if (lv.z == c) { int p = atomicAdd(&cnt, 1); if (p < MEMCAP) mem[p] = base + 2; }
            if (lv.w == c) { int p = atomicAdd(&cnt, 1); if (p < MEMCAP) mem[p] = base + 3; }
        }
        __syncthreads();
        int n = cnt < MEMCAP ? cnt : MEMCAP;
        float vmax = 0.0f;
        if (n >= 2) {
            const float4* x4 = reinterpret_cast<const float4*>(x);
            // stage rows + tree mags (bit-exact shuffle tree, as before)
            for (int m = w; m < n; m += 4) {
                int row = mem[m];
                float4 v = x4[(size_t)row * 64 + lane];
                if (m < ROWCAP)
                    *reinterpret_cast<float4*>(&rowS[m][lane << 2]) = v;
                float s = v.x * v.x + v.y * v.y + v.z * v.z + v.w * v.w;
                #pragma unroll
                for (int o = 32; o > 0; o >>= 1) s += __shfl_xor(s, o);
                if (lane == 0) magS[m] = s;
            }
            __syncthreads();
            int npairs = n * (n - 1) / 2;
            for (int p = r * 4 + w; p < npairs; p += 16) {   // residue-unique pairs
                int a = 0, rem = p;                           // unrank (a-major)
                while (rem >= n - 1 - a) { rem -= n - 1 - a; ++a; }
                int b = a + 1 + rem;
                float4 va = (a < ROWCAP)
                    ? *reinterpret_cast<float4*>(&rowS[a][lane << 2])
                    : x4[(size_t)mem[a] * 64 + lane];
                float4 vb = (b < ROWCAP)
                    ? *reinterpret_cast<float4*>(&rowS[b][lane << 2])
                    : x4[(size_t)mem[b] * 64 + lane];
                float s = va.x * vb.x + va.y * vb.y + va.z * vb.z + va.w * vb.w;
                #pragma unroll
                for (int o = 32; o > 0; o >>= 1) s += __shfl_xor(s, o);
                float d2 = magS[a] + magS[b] - 2.0f * s;     // add commutes: bit-same
                float d  = sqrtf(fmaxf(d2, 0.0f));
                d = fminf(fmaxf(d, 1e-12f), 1e12f);
                vmax = fmaxf(vmax, d);
            }
        }
        if (lane == 0) wred[w] = vmax;
        __syncthreads();
        if (t == 0) {
            float m = fmaxf(fmaxf(wred[0], wred[1]), fmaxf(wred[2], wred[3]));
            if (m > 0.0f) {
                unsigned int bits = __float_as_uint(m);
                volatile unsigned int* p = ws + (blockIdx.x & (NSLOT - 1)) * 16;
                if (bits > *p) atomicMax((unsigned int*)p, bits);
            }
        }
    }
}

// One block, 64 threads: reduce the slot arrays, write the scalar output.
__global__ void k_final(const unsigned int* __restrict__ ws, float* __restrict__ out) {
    int t = threadIdx.x;               // 0..63
    unsigned int mx = ws[t * 16];            // intra max bits (0 if empty)
    unsigned int mc = ws[1024 + t * 16];     // inter ~min bits (0 if empty)
    #pragma unroll
    for (int o = 32; o > 0; o >>= 1) {
        unsigned int ax = __shfl_xor((int)mx, o);
        unsigned int ac = __shfl_xor((int)mc, o);
        mx = mx > ax ? mx : ax;
        mc = mc > ac ? mc : ac;
    }
    if (t == 0) {
        float M = fmaxf(__uint_as_float(mx), 1e-12f);    // diagonal clamp floor
        float r = 1.0f / M;
        float li2 = 2.0f / (r + r);                      // harmonic mean of [M,M] * 2
        float m = fminf(__uint_as_float(~mc), 1e12f);
        float linter = fminf(fmaxf(5.0f - m, 0.0f), 1e6f);
        out[0] = li2 + linter;                           // ALPHA = BETA = 1
    }
}

extern "C" void kernel_launch(void* const* d_in, const int* in_sizes, int n_in,
                              void* d_out, int out_size, void* d_ws, size_t ws_size,
                              hipStream_t stream) {
    const float* x       = (const float*)d_in[0];
    const int*   labels  = (const int*)d_in[1];
    const float* centers = (const float*)d_in[2];
    unsigned int* ws     = (unsigned int*)d_ws;
    float*        out    = (float*)d_out;

    hipMemsetAsync(d_ws, 0x00, 8192, stream);   // umax + uminC slots

    k_main<<<NBLK, 256, 0, stream>>>(x, labels, centers, ws, out);
    k_final<<<1, 64, 0, stream>>>(ws, out);
}

// Round 7
// 95.444 us; speedup vs baseline: 3.1359x; 1.0009x over previous
//
#include <hip/hip_runtime.h>
#include <math.h>

#define BATCH 8192
#define FEAT  256
#define NCLS  1000

#define NGEMM  256                  // 16x16 grid of 64x64 inter tiles
#define REPL   4                    // replica blocks per class (tail killer)
#define NINTRA (REPL*NCLS)          // 4000
#define NBLK   (NGEMM + NINTRA)     // 4256
#define ROWCAP 16                   // rows staged in LDS per class
#define MEMCAP 96                   // hard cap on class size (P(n>40) ~ 1e-15)

// ws (f32): [0,256)           per-GEMM-block inter min (plain store, no init needed)
//           [256, 256+4000)   per-intra-block max      (plain store, no init needed)
// Every slot is unconditionally written every call -> harness 0xAA poison harmless.

// LDS union:
//   GEMM : As[32][68] (8704) | Bs[32][68] (8704) | cmagS[64] (256) = 17664 B
//   intra: rowS[16][256] (16384) | mem[96] (384) | magS[96] (384)  = 17152 B
__global__ __launch_bounds__(256) void k_main(const float* __restrict__ x,
                                              const int* __restrict__ labels,
                                              const float* __restrict__ centers,
                                              float* __restrict__ ws) {
    __shared__ __align__(16) char raw[17664];
    __shared__ float wred[4];
    __shared__ int cnt;
    int t = threadIdx.x;
    int lane = t & 63, w = t >> 6;

    if (blockIdx.x < NGEMM) {
        // ---------------- inter: 64x64 f32 tile, 4x4 register blocking ----
        float (*As)[68] = reinterpret_cast<float(*)[68]>(raw);
        float (*Bs)[68] = reinterpret_cast<float(*)[68]>(raw + 8704);
        float* cmagS    = reinterpret_cast<float*>(raw + 17408);
        int bi = blockIdx.x >> 4, bj = blockIdx.x & 15;
        int i0 = bi * 64, j0 = bj * 64;

        // inline cmag for this tile's j-rows (bit-exact rownorm tree)
        for (int q = w; q < 64; q += 4) {
            int gj = j0 + q;
            float s = 0.0f;
            if (gj < NCLS) {
                float4 v = reinterpret_cast<const float4*>(centers + (size_t)gj * FEAT)[lane];
                s = v.x * v.x + v.y * v.y + v.z * v.z + v.w * v.w;
                #pragma unroll
                for (int o = 32; o > 0; o >>= 1) s += __shfl_xor(s, o);
            }
            if (lane == 0) cmagS[q] = 2.0f * s;
        }
        // (k-loop barriers below order cmagS writes before the epilogue reads)

        int tx = t & 15, ty = t >> 4;
        float acc[4][4] = {{0.f}};
        for (int kk = 0; kk < FEAT; kk += 32) {
            #pragma unroll
            for (int e = t; e < 512; e += 256) {
                int row = e >> 3, q = e & 7;
                int col = kk + q * 4;
                int gi = i0 + row, gj = j0 + row;
                float4 av = (gi < NCLS)
                    ? *reinterpret_cast<const float4*>(centers + (size_t)gi * FEAT + col)
                    : make_float4(0.f, 0.f, 0.f, 0.f);
                float4 bv = (gj < NCLS)
                    ? *reinterpret_cast<const float4*>(centers + (size_t)gj * FEAT + col)
                    : make_float4(0.f, 0.f, 0.f, 0.f);
                As[q * 4 + 0][row] = av.x; As[q * 4 + 1][row] = av.y;
                As[q * 4 + 2][row] = av.z; As[q * 4 + 3][row] = av.w;
                Bs[q * 4 + 0][row] = bv.x; Bs[q * 4 + 1][row] = bv.y;
                Bs[q * 4 + 2][row] = bv.z; Bs[q * 4 + 3][row] = bv.w;
            }
            __syncthreads();
            #pragma unroll
            for (int k = 0; k < 32; ++k) {   // sequential k: same rounding as before
                float4 a4 = *reinterpret_cast<float4*>(&As[k][ty * 4]);
                float4 b4 = *reinterpret_cast<float4*>(&Bs[k][tx * 4]);
                acc[0][0] += a4.x * b4.x; acc[0][1] += a4.x * b4.y;
                acc[0][2] += a4.x * b4.z; acc[0][3] += a4.x * b4.w;
                acc[1][0] += a4.y * b4.x; acc[1][1] += a4.y * b4.y;
                acc[1][2] += a4.y * b4.z; acc[1][3] += a4.y * b4.w;
                acc[2][0] += a4.z * b4.x; acc[2][1] += a4.z * b4.y;
                acc[2][2] += a4.z * b4.z; acc[2][3] += a4.z * b4.w;
                acc[3][0] += a4.w * b4.x; acc[3][1] += a4.w * b4.y;
                acc[3][2] += a4.w * b4.z; acc[3][3] += a4.w * b4.w;
            }
            __syncthreads();
        }
        float lmin = 1e30f;
        #pragma unroll
        for (int jj = 0; jj < 4; ++jj) {
            int j = j0 + tx * 4 + jj;
            if (j < NCLS) {
                float cm = cmagS[tx * 4 + jj];
                #pragma unroll
                for (int ii = 0; ii < 4; ++ii) {
                    int i = i0 + ty * 4 + ii;
                    if (i < NCLS) {
                        float v = cm - 2.0f * acc[ii][jj];
                        v = fminf(fmaxf(v, 1e-12f), 1e12f);
                        lmin = fminf(lmin, v);
                    }
                }
            }
        }
        #pragma unroll
        for (int o = 32; o > 0; o >>= 1) lmin = fminf(lmin, __shfl_xor(lmin, o));
        if (lane == 0) wred[w] = lmin;
        __syncthreads();
        if (t == 0) {
            float m = fminf(fminf(wred[0], wred[1]), fminf(wred[2], wred[3]));
            ws[blockIdx.x] = m;                         // plain store, unique slot
        }
    } else {
        // ---------------- intra: class-owned replica blocks ----------------
        int bid = blockIdx.x - NGEMM;
        int c   = bid >> 2;            // class id 0..999
        int r   = bid & 3;             // replica 0..3
        float (*rowS)[256] = reinterpret_cast<float(*)[256]>(raw);
        int*   mem  = reinterpret_cast<int*>(raw + 16384);
        float* magS = reinterpret_cast<float*>(raw + 16768);

        if (t == 0) cnt = 0;
        __syncthreads();
        // find members: coalesced int4 scan of labels (L2-resident, 32KB)
        const int4* gl4 = reinterpret_cast<const int4*>(labels);
        #pragma unroll
        for (int k = 0; k < 8; ++k) {
            int4 lv = gl4[t + (k << 8)];
            int base = (t + (k << 8)) << 2;
            if (lv.x == c) { int p = atomicAdd(&cnt, 1); if (p < MEMCAP) mem[p] = base;     }
            if (lv.y == c) { int p = atomicAdd(&cnt, 1); if (p < MEMCAP) mem[p] = base + 1; }
            if (lv.z == c) { int p = atomicAdd(&cnt, 1); if (p < MEMCAP) mem[p] = base + 2; }
            if (lv.w == c) { int p = atomicAdd(&cnt, 1); if (p < MEMCAP) mem[p] = base + 3; }
        }
        __syncthreads();
        int n = cnt < MEMCAP ? cnt : MEMCAP;
        float vmax = 0.0f;
        if (n >= 2) {
            const float4* x4 = reinterpret_cast<const float4*>(x);
            // stage rows + tree mags (bit-exact shuffle tree, as before)
            for (int m = w; m < n; m += 4) {
                int row = mem[m];
                float4 v = x4[(size_t)row * 64 + lane];
                if (m < ROWCAP)
                    *reinterpret_cast<float4*>(&rowS[m][lane << 2]) = v;
                float s = v.x * v.x + v.y * v.y + v.z * v.z + v.w * v.w;
                #pragma unroll
                for (int o = 32; o > 0; o >>= 1) s += __shfl_xor(s, o);
                if (lane == 0) magS[m] = s;
            }
            __syncthreads();
            int npairs = n * (n - 1) / 2;
            for (int p = r * 4 + w; p < npairs; p += 16) {   // residue-unique pairs
                int a = 0, rem = p;                           // unrank (a-major)
                while (rem >= n - 1 - a) { rem -= n - 1 - a; ++a; }
                int b = a + 1 + rem;
                float4 va = (a < ROWCAP)
                    ? *reinterpret_cast<float4*>(&rowS[a][lane << 2])
                    : x4[(size_t)mem[a] * 64 + lane];
                float4 vb = (b < ROWCAP)
                    ? *reinterpret_cast<float4*>(&rowS[b][lane << 2])
                    : x4[(size_t)mem[b] * 64 + lane];
                float s = va.x * vb.x + va.y * vb.y + va.z * vb.z + va.w * vb.w;
                #pragma unroll
                for (int o = 32; o > 0; o >>= 1) s += __shfl_xor(s, o);
                float d2 = magS[a] + magS[b] - 2.0f * s;     // add commutes: bit-same
                float d  = sqrtf(fmaxf(d2, 0.0f));
                d = fminf(fmaxf(d, 1e-12f), 1e12f);
                vmax = fmaxf(vmax, d);
            }
        }
        if (lane == 0) wred[w] = vmax;
        __syncthreads();
        if (t == 0) {
            float m = fmaxf(fmaxf(wred[0], wred[1]), fmaxf(wred[2], wred[3]));
            ws[NGEMM + bid] = m;                        // plain store, unique slot
        }
    }
}

// One block, 256 threads: reduce the 4256 per-block partials, write the scalar.
__global__ __launch_bounds__(256) void k_final(const float* __restrict__ ws,
                                               float* __restrict__ out) {
    __shared__ float smx[4], smn[4];
    int t = threadIdx.x, lane = t & 63, w = t >> 6;
    float mn = 1e30f, mx = 0.0f;
    for (int i = t; i < NGEMM; i += 256)  mn = fminf(mn, ws[i]);
    for (int i = t; i < NINTRA; i += 256) mx = fmaxf(mx, ws[NGEMM + i]);
    #pragma unroll
    for (int o = 32; o > 0; o >>= 1) {
        mx = fmaxf(mx, __shfl_xor(mx, o));
        mn = fminf(mn, __shfl_xor(mn, o));
    }
    if (lane == 0) { smx[w] = mx; smn[w] = mn; }
    __syncthreads();
    if (t == 0) {
        mx = fmaxf(fmaxf(smx[0], smx[1]), fmaxf(smx[2], smx[3]));
        mn = fminf(fminf(smn[0], smn[1]), fminf(smn[2], smn[3]));
        float M = fmaxf(mx, 1e-12f);                  // diagonal clamp floor
        float r = 1.0f / M;
        float li2 = 2.0f / (r + r);                   // harmonic mean of [M,M] * 2
        float m = fminf(mn, 1e12f);
        float linter = fminf(fmaxf(5.0f - m, 0.0f), 1e6f);
        out[0] = li2 + linter;                        // ALPHA = BETA = 1
    }
}

extern "C" void kernel_launch(void* const* d_in, const int* in_sizes, int n_in,
                              void* d_out, int out_size, void* d_ws, size_t ws_size,
                              hipStream_t stream) {
    const float* x       = (const float*)d_in[0];
    const int*   labels  = (const int*)d_in[1];
    const float* centers = (const float*)d_in[2];
    float*        ws     = (float*)d_ws;
    float*        out    = (float*)d_out;

    k_main<<<NBLK, 256, 0, stream>>>(x, labels, centers, ws);
    k_final<<<1, 256, 0, stream>>>(ws, out);
}